// Round 1
// baseline (4695.572 us; speedup 1.0000x reference)
//
#include <hip/hip_runtime.h>
#include <hip/hip_bf16.h>
#include <math.h>

#define LN_EPS 1e-5f

constexpr int Bb = 8, Ss = 2048, Ee = 512, Ll = 6, Ff = 2048, Cc = 10;
constexpr int Nn = Bb * Ss;  // 16384 token positions

// ---------------- positional encoding table ----------------
__global__ void pe_kernel(float* __restrict__ pe) {
    int p = blockIdx.x * blockDim.x + threadIdx.x;  // pair index
    int total = Ss * (Ee / 2);
    if (p >= total) return;
    int s = p / (Ee / 2);
    int i = p % (Ee / 2);
    float div = expf(float(2 * i) * (-logf(10000.0f) / float(Ee)));
    float ang = float(s) * div;
    pe[s * Ee + 2 * i]     = sinf(ang);
    pe[s * Ee + 2 * i + 1] = cosf(ang);
}

// ---------------- embedding + PE ----------------
__global__ void embed_kernel(const int* __restrict__ tokens,
                             const float* __restrict__ emb,
                             const float* __restrict__ pe,
                             float* __restrict__ x) {
    int idx = blockIdx.x * blockDim.x + threadIdx.x;  // float4 index
    int total = Nn * Ee / 4;
    if (idx >= total) return;
    int n  = idx / (Ee / 4);
    int e4 = idx % (Ee / 4);
    int tok = tokens[n];
    int s = n % Ss;
    float4 a = *(const float4*)(emb + (size_t)tok * Ee + e4 * 4);
    float4 p = *(const float4*)(pe + (size_t)s * Ee + e4 * 4);
    float4 o;
    o.x = a.x + p.x; o.y = a.y + p.y; o.z = a.z + p.z; o.w = a.w + p.w;
    *(float4*)(x + (size_t)n * Ee + e4 * 4) = o;
}

// ---------------- generic NT GEMM: C[m,f] = sum_k A[m,k]*W[f,k] + bias[f] ----
// MODE 1: A[m,k] = cos(X[m,k] + theta[k])
// MODE 2: A[m,k] = relu(dot4(z[m,:], W1[k,:]) + b1[k])   (fused FFN hidden)
template <int MODE>
__global__ __launch_bounds__(256) void gemm_nt(
    const float* __restrict__ A,     // MODE1: X (M x K)
    const float* __restrict__ W,     // Nout x K
    const float* __restrict__ bias,  // Nout
    const float* __restrict__ theta, // MODE1: K
    const float* __restrict__ z,     // MODE2: M x 4
    const float* __restrict__ W1,    // MODE2: K x 4
    const float* __restrict__ b1,    // MODE2: K
    float* __restrict__ Cmat, int M, int Nout, int K) {
    constexpr int BM = 64, BN = 64, BK = 16;
    __shared__ float As[BK][BM + 4];
    __shared__ float Bs[BK][BN + 4];
    int tid = threadIdx.x;
    int ty = tid / 16, tx = tid % 16;
    int row0 = blockIdx.x * BM;
    int col0 = blockIdx.y * BN;
    int lr = tid / 4;          // 0..63  row within tile
    int lc4 = (tid % 4) * 4;   // k-col 0,4,8,12
    float acc[4][4] = {};
    for (int k0 = 0; k0 < K; k0 += BK) {
        float4 av;
        if (MODE == 2) {
            float4 zr = *(const float4*)(z + (size_t)(row0 + lr) * 4);
            float v[4];
#pragma unroll
            for (int j = 0; j < 4; j++) {
                int f = k0 + lc4 + j;
                float4 w1 = *(const float4*)(W1 + (size_t)f * 4);
                float t = zr.x * w1.x + zr.y * w1.y + zr.z * w1.z + zr.w * w1.w + b1[f];
                v[j] = t > 0.0f ? t : 0.0f;
            }
            av = make_float4(v[0], v[1], v[2], v[3]);
        } else {
            av = *(const float4*)(A + (size_t)(row0 + lr) * K + k0 + lc4);
            if (MODE == 1) {
                av.x = cosf(av.x + theta[k0 + lc4 + 0]);
                av.y = cosf(av.y + theta[k0 + lc4 + 1]);
                av.z = cosf(av.z + theta[k0 + lc4 + 2]);
                av.w = cosf(av.w + theta[k0 + lc4 + 3]);
            }
        }
        As[lc4 + 0][lr] = av.x;
        As[lc4 + 1][lr] = av.y;
        As[lc4 + 2][lr] = av.z;
        As[lc4 + 3][lr] = av.w;
        float4 bv = *(const float4*)(W + (size_t)(col0 + lr) * K + k0 + lc4);
        Bs[lc4 + 0][lr] = bv.x;
        Bs[lc4 + 1][lr] = bv.y;
        Bs[lc4 + 2][lr] = bv.z;
        Bs[lc4 + 3][lr] = bv.w;
        __syncthreads();
#pragma unroll
        for (int kk = 0; kk < BK; kk++) {
            float4 a = *(const float4*)(&As[kk][ty * 4]);
            float4 b = *(const float4*)(&Bs[kk][tx * 4]);
            acc[0][0] += a.x * b.x; acc[0][1] += a.x * b.y; acc[0][2] += a.x * b.z; acc[0][3] += a.x * b.w;
            acc[1][0] += a.y * b.x; acc[1][1] += a.y * b.y; acc[1][2] += a.y * b.z; acc[1][3] += a.y * b.w;
            acc[2][0] += a.z * b.x; acc[2][1] += a.z * b.y; acc[2][2] += a.z * b.z; acc[2][3] += a.z * b.w;
            acc[3][0] += a.w * b.x; acc[3][1] += a.w * b.y; acc[3][2] += a.w * b.z; acc[3][3] += a.w * b.w;
        }
        __syncthreads();
    }
#pragma unroll
    for (int i = 0; i < 4; i++) {
        int row = row0 + ty * 4 + i;
        int col = col0 + tx * 4;
        float4 o;
        o.x = acc[i][0] + bias[col + 0];
        o.y = acc[i][1] + bias[col + 1];
        o.z = acc[i][2] + bias[col + 2];
        o.w = acc[i][3] + bias[col + 3];
        *(float4*)(Cmat + (size_t)row * Nout + col) = o;
    }
}

// ---------------- residual + layernorm (in-place on x) ----------------
__global__ __launch_bounds__(256) void ln_kernel(float* __restrict__ x,
                                                 const float* __restrict__ tmp,
                                                 const float* __restrict__ g,
                                                 const float* __restrict__ b) {
    int row = blockIdx.x;
    int tid = threadIdx.x;
    float* xr = x + (size_t)row * Ee;
    const float* tr = tmp + (size_t)row * Ee;
    float v0 = xr[tid] + tr[tid];
    float v1 = xr[tid + 256] + tr[tid + 256];
    __shared__ float red[256];
    red[tid] = v0 + v1;
    __syncthreads();
    for (int s = 128; s > 0; s >>= 1) {
        if (tid < s) red[tid] += red[tid + s];
        __syncthreads();
    }
    float mu = red[0] / float(Ee);
    __syncthreads();
    float d0 = v0 - mu, d1 = v1 - mu;
    red[tid] = d0 * d0 + d1 * d1;
    __syncthreads();
    for (int s = 128; s > 0; s >>= 1) {
        if (tid < s) red[tid] += red[tid + s];
        __syncthreads();
    }
    float var = red[0] / float(Ee);
    float rs = rsqrtf(var + LN_EPS);
    xr[tid]       = d0 * rs * g[tid] + b[tid];
    xr[tid + 256] = d1 * rs * g[tid + 256] + b[tid + 256];
}

// ---------------- z = cos(x[:, :4]) * cos(phi) ----------------
__global__ void z_kernel(const float* __restrict__ x,
                         const float* __restrict__ phi,
                         float* __restrict__ z) {
    int n = blockIdx.x * blockDim.x + threadIdx.x;
    if (n >= Nn) return;
    float4 v = *(const float4*)(x + (size_t)n * Ee);
    float4 o;
    o.x = cosf(v.x) * cosf(phi[0]);
    o.y = cosf(v.y) * cosf(phi[1]);
    o.z = cosf(v.z) * cosf(phi[2]);
    o.w = cosf(v.w) * cosf(phi[3]);
    *(float4*)(z + (size_t)n * 4) = o;
}

// ---------------- mean pool over S + classifier ----------------
__global__ __launch_bounds__(256) void pool_cls_kernel(const float* __restrict__ x,
                                                       const float* __restrict__ clsW,
                                                       const float* __restrict__ clsb,
                                                       float* __restrict__ out) {
    int b = blockIdx.x;
    int tid = threadIdx.x;
    __shared__ float pooled[Ee];
    float s0 = 0.0f, s1 = 0.0f;
    for (int s = 0; s < Ss; s++) {
        const float* row = x + ((size_t)b * Ss + s) * Ee;
        s0 += row[tid];
        s1 += row[tid + 256];
    }
    pooled[tid] = s0 / float(Ss);
    pooled[tid + 256] = s1 / float(Ss);
    __syncthreads();
    __shared__ float red[256];
    for (int c = 0; c < Cc; c++) {
        float p = pooled[tid] * clsW[(size_t)c * Ee + tid] +
                  pooled[tid + 256] * clsW[(size_t)c * Ee + tid + 256];
        red[tid] = p;
        __syncthreads();
        for (int s2 = 128; s2 > 0; s2 >>= 1) {
            if (tid < s2) red[tid] += red[tid + s2];
            __syncthreads();
        }
        if (tid == 0) out[b * Cc + c] = red[0] + clsb[c];
        __syncthreads();
    }
}

extern "C" void kernel_launch(void* const* d_in, const int* in_sizes, int n_in,
                              void* d_out, int out_size, void* d_ws, size_t ws_size,
                              hipStream_t stream) {
    const int*   tokens     = (const int*)d_in[0];
    const float* emb        = (const float*)d_in[1];
    const float* theta_attn = (const float*)d_in[2];
    const float* combine_W  = (const float*)d_in[3];
    const float* combine_b  = (const float*)d_in[4];
    const float* ln1_g      = (const float*)d_in[5];
    const float* ln1_b      = (const float*)d_in[6];
    const float* phi_ffn    = (const float*)d_in[7];
    const float* lin1_W     = (const float*)d_in[8];
    const float* lin1_b     = (const float*)d_in[9];
    const float* lin2_W     = (const float*)d_in[10];
    const float* lin2_b     = (const float*)d_in[11];
    const float* ln2_g      = (const float*)d_in[12];
    const float* ln2_b      = (const float*)d_in[13];
    const float* cls_W      = (const float*)d_in[14];
    const float* cls_b      = (const float*)d_in[15];
    float* out = (float*)d_out;

    float* pe  = (float*)d_ws;              // Ss*Ee
    float* x   = pe + (size_t)Ss * Ee;      // Nn*Ee
    float* tmp = x + (size_t)Nn * Ee;       // Nn*Ee
    float* z   = tmp + (size_t)Nn * Ee;     // Nn*4

    // PE table
    {
        int total = Ss * (Ee / 2);
        pe_kernel<<<(total + 255) / 256, 256, 0, stream>>>(pe);
    }
    // embedding + PE
    {
        int total = Nn * Ee / 4;
        embed_kernel<<<(total + 255) / 256, 256, 0, stream>>>(tokens, emb, pe, x);
    }

    dim3 gemm_grid(Nn / 64, Ee / 64);  // (256, 8)
    for (int l = 0; l < Ll; l++) {
        const float* thl  = theta_attn + (size_t)l * Ee;      // H*NQ == E
        const float* cWl  = combine_W + (size_t)l * Ee * Ee;
        const float* cbl  = combine_b + (size_t)l * Ee;
        const float* g1   = ln1_g + (size_t)l * Ee;
        const float* b1n  = ln1_b + (size_t)l * Ee;
        const float* phil = phi_ffn + (size_t)l * 4;
        const float* w1l  = lin1_W + (size_t)l * Ff * 4;
        const float* b1l  = lin1_b + (size_t)l * Ff;
        const float* w2l  = lin2_W + (size_t)l * Ee * Ff;
        const float* b2l  = lin2_b + (size_t)l * Ee;
        const float* g2   = ln2_g + (size_t)l * Ee;
        const float* b2n  = ln2_b + (size_t)l * Ee;

        // attn = cos(x + theta) @ combine_W^T + combine_b
        gemm_nt<1><<<gemm_grid, 256, 0, stream>>>(x, cWl, cbl, thl,
                                                  nullptr, nullptr, nullptr,
                                                  tmp, Nn, Ee, Ee);
        // x = LN(x + attn)
        ln_kernel<<<Nn, 256, 0, stream>>>(x, tmp, g1, b1n);
        // z = cos(x[:, :4]) * cos(phi)
        z_kernel<<<(Nn + 255) / 256, 256, 0, stream>>>(x, phil, z);
        // ffn = relu(z @ W1^T + b1) @ W2^T + b2   (h fused into A-tile)
        gemm_nt<2><<<gemm_grid, 256, 0, stream>>>(nullptr, w2l, b2l, nullptr,
                                                  z, w1l, b1l,
                                                  tmp, Nn, Ee, Ff);
        // x = LN(x + ffn)
        ln_kernel<<<Nn, 256, 0, stream>>>(x, tmp, g2, b2n);
    }

    pool_cls_kernel<<<Bb, 256, 0, stream>>>(x, cls_W, cls_b, out);
}

// Round 5
// 846.498 us; speedup vs baseline: 5.5471x; 5.5471x over previous
//
#include <hip/hip_runtime.h>
#include <hip/hip_bf16.h>
#include <math.h>

#define LN_EPS 1e-5f

constexpr int Bb = 8, Ss = 2048, Ee = 512, Ll = 6, Ff = 2048, Cc = 10;
constexpr int Nn = Bb * Ss;  // 16384 rows

typedef __attribute__((ext_vector_type(8))) short short8v;
typedef __attribute__((ext_vector_type(4))) float f32x4;

__device__ __forceinline__ unsigned short f2bf(float f) {
    unsigned int b = __float_as_uint(f);
    b += 0x7FFFu + ((b >> 16) & 1u);   // RNE
    return (unsigned short)(b >> 16);
}

__device__ __forceinline__ float fastcos(float x) {
    float r = x * 0.15915494309189535f;     // radians -> revolutions
    r = __builtin_amdgcn_fractf(r);         // reduce to [0,1)
    return __builtin_amdgcn_cosf(r);        // v_cos_f32
}

// ---------------- positional encoding table ----------------
__global__ void pe_kernel(float* __restrict__ pe) {
    int p = blockIdx.x * blockDim.x + threadIdx.x;
    int total = Ss * (Ee / 2);
    if (p >= total) return;
    int s = p / (Ee / 2);
    int i = p % (Ee / 2);
    float div = expf(float(2 * i) * (-logf(10000.0f) / float(Ee)));
    float ang = float(s) * div;
    pe[s * Ee + 2 * i]     = sinf(ang);
    pe[s * Ee + 2 * i + 1] = cosf(ang);
}

// ---------------- embedding + PE ----------------
__global__ void embed_kernel(const int* __restrict__ tokens,
                             const float* __restrict__ emb,
                             const float* __restrict__ pe,
                             float* __restrict__ x) {
    int idx = blockIdx.x * blockDim.x + threadIdx.x;
    int total = Nn * Ee / 4;
    if (idx >= total) return;
    int n  = idx / (Ee / 4);
    int e4 = idx % (Ee / 4);
    int tok = tokens[n];
    int s = n % Ss;
    f32x4 a = *(const f32x4*)(emb + (size_t)tok * Ee + e4 * 4);
    f32x4 p = *(const f32x4*)(pe + (size_t)s * Ee + e4 * 4);
    f32x4 o = a + p;
    *(f32x4*)(x + (size_t)n * Ee + e4 * 4) = o;
}

// ---------------- fp32 -> bf16 weight conversion ----------------
__global__ void cvt_bf16(const float* __restrict__ in,
                         unsigned short* __restrict__ out, int n4) {
    int i = blockIdx.x * blockDim.x + threadIdx.x;
    if (i >= n4) return;
    f32x4 v = *(const f32x4*)(in + (size_t)i * 4);
    ushort4 o;
    o.x = f2bf(v.x); o.y = f2bf(v.y); o.z = f2bf(v.z); o.w = f2bf(v.w);
    *(ushort4*)(out + (size_t)i * 4) = o;
}

// =========== MFMA GEMM: Cout = Agen @ Wb^T + bias + xres ===========
// N fixed at 512 (output width = E). K = 512 (MODE 1) or 2048 (MODE 2).
// MODE 1: A[m][k] = bf16(cos(x[m][k] + theta[k]))        (x fp32, stride K)
// MODE 2: A[m][k] = bf16(relu(dot4(z[m],W1[k]) + b1[k])) (z fp32, stride 4)
// Tile 128x128, BK=64, 4 waves (2x2 of 64x64), 16x16x32 bf16 MFMA.
// LDS rows 128B, chunk-XOR swizzle (c ^= row&7) -> conflict-free ds_read_b128.
template <int MODE>
__global__ __launch_bounds__(256) void gemm_mfma(
    const float* __restrict__ Xsrc,           // MODE1: x (MxK); MODE2: z (Mx4)
    const float* __restrict__ P0,             // MODE1: theta[K]; MODE2: W1[Kx4]
    const float* __restrict__ P1,             // MODE2: b1[K]
    const unsigned short* __restrict__ Wb,    // N x K bf16
    const float* __restrict__ bias,           // N
    const float* __restrict__ xres,           // M x 512 residual
    float* __restrict__ Cout,                 // M x 512
    int M, int K) {
    __shared__ unsigned short As[128 * 64];
    __shared__ unsigned short Bs[128 * 64];
    const int tid  = threadIdx.x;
    const int lane = tid & 63;
    const int wr   = (tid >> 7) & 1;
    const int wc   = (tid >> 6) & 1;
    const int row0 = blockIdx.x * 128;
    const int col0 = blockIdx.y * 128;
    const int sc   = tid & 7;        // staging chunk 0..7 (8 bf16 each)
    const int srb  = tid >> 3;       // staging row base 0..31 (row = i*32+srb)

    f32x4 acc[4][4];
#pragma unroll
    for (int m = 0; m < 4; m++)
#pragma unroll
        for (int n = 0; n < 4; n++) acc[m][n] = {0.f, 0.f, 0.f, 0.f};

    f32x4 zr[4];
    if (MODE == 2) {
#pragma unroll
        for (int i = 0; i < 4; i++)
            zr[i] = *(const f32x4*)(Xsrc + (size_t)(row0 + i * 32 + srb) * 4);
    }

    float   xr[4][8];
    float   th[8];
    f32x4   w1r[8];
    float   b1r[8];
    short8v braw[4];
    short8v apk[4];

    auto LOAD = [&](int k0) {
#pragma unroll
        for (int i = 0; i < 4; i++) {
            braw[i] = *(const short8v*)(Wb + (size_t)(col0 + i * 32 + srb) * K + k0 + sc * 8);
        }
        if (MODE == 1) {
            const float* tp = P0 + k0 + sc * 8;
            f32x4 t0 = *(const f32x4*)(tp);
            f32x4 t1 = *(const f32x4*)(tp + 4);
            th[0] = t0.x; th[1] = t0.y; th[2] = t0.z; th[3] = t0.w;
            th[4] = t1.x; th[5] = t1.y; th[6] = t1.z; th[7] = t1.w;
#pragma unroll
            for (int i = 0; i < 4; i++) {
                const float* xp = Xsrc + (size_t)(row0 + i * 32 + srb) * K + k0 + sc * 8;
                f32x4 a0 = *(const f32x4*)(xp);
                f32x4 a1 = *(const f32x4*)(xp + 4);
                xr[i][0] = a0.x; xr[i][1] = a0.y; xr[i][2] = a0.z; xr[i][3] = a0.w;
                xr[i][4] = a1.x; xr[i][5] = a1.y; xr[i][6] = a1.z; xr[i][7] = a1.w;
            }
        } else {
#pragma unroll
            for (int j = 0; j < 8; j++)
                w1r[j] = *(const f32x4*)(P0 + (size_t)(k0 + sc * 8 + j) * 4);
            f32x4 bb0 = *(const f32x4*)(P1 + k0 + sc * 8);
            f32x4 bb1 = *(const f32x4*)(P1 + k0 + sc * 8 + 4);
            b1r[0] = bb0.x; b1r[1] = bb0.y; b1r[2] = bb0.z; b1r[3] = bb0.w;
            b1r[4] = bb1.x; b1r[5] = bb1.y; b1r[6] = bb1.z; b1r[7] = bb1.w;
        }
    };

    auto PACK = [&]() {
        if (MODE == 1) {
#pragma unroll
            for (int i = 0; i < 4; i++)
#pragma unroll
                for (int j = 0; j < 8; j++)
                    apk[i][j] = (short)f2bf(fastcos(xr[i][j] + th[j]));
        } else {
#pragma unroll
            for (int i = 0; i < 4; i++)
#pragma unroll
                for (int j = 0; j < 8; j++) {
                    float t = zr[i].x * w1r[j].x + zr[i].y * w1r[j].y +
                              zr[i].z * w1r[j].z + zr[i].w * w1r[j].w + b1r[j];
                    t = fmaxf(t, 0.f);
                    apk[i][j] = (short)f2bf(t);
                }
        }
    };

    auto DSW = [&]() {
#pragma unroll
        for (int i = 0; i < 4; i++) {
            int row  = i * 32 + srb;
            int phys = (sc ^ (row & 7)) * 8;
            *(short8v*)(&As[row * 64 + phys]) = apk[i];
            *(short8v*)(&Bs[row * 64 + phys]) = braw[i];
        }
    };

    auto COMPUTE = [&]() {
#pragma unroll
        for (int ks = 0; ks < 2; ks++) {
            const int k8 = ks * 4 + (lane >> 4);
            short8v aF[4], bF[4];
#pragma unroll
            for (int m = 0; m < 4; m++) {
                int row = wr * 64 + m * 16 + (lane & 15);
                aF[m] = *(const short8v*)(&As[row * 64 + ((k8 ^ (row & 7)) * 8)]);
            }
#pragma unroll
            for (int n = 0; n < 4; n++) {
                int row = wc * 64 + n * 16 + (lane & 15);
                bF[n] = *(const short8v*)(&Bs[row * 64 + ((k8 ^ (row & 7)) * 8)]);
            }
#pragma unroll
            for (int m = 0; m < 4; m++)
#pragma unroll
                for (int n = 0; n < 4; n++)
                    acc[m][n] = __builtin_amdgcn_mfma_f32_16x16x32_bf16(
                        aF[m], bF[n], acc[m][n], 0, 0, 0);
        }
    };

    const int NK = K >> 6;
    LOAD(0);
    for (int kt = 0; kt < NK; ++kt) {
        PACK();
        if (kt) __syncthreads();   // prior COMPUTE's LDS reads done
        DSW();
        __syncthreads();           // tile visible
        if (kt + 1 < NK) LOAD((kt + 1) << 6);  // overlap with MFMA
        COMPUTE();
    }

#pragma unroll
    for (int m = 0; m < 4; m++) {
#pragma unroll
        for (int n = 0; n < 4; n++) {
            int colg = col0 + wc * 64 + n * 16 + (lane & 15);
            float bv = bias[colg];
#pragma unroll
            for (int j = 0; j < 4; j++) {
                int rowg = row0 + wr * 64 + m * 16 + ((lane >> 4) * 4) + j;
                size_t off = (size_t)rowg * 512 + colg;
                Cout[off] = acc[m][n][j] + bv + xres[off];
            }
        }
    }
}

// ---------------- LN (wave per row) on tmp -> x; optional z fusion ------
__global__ __launch_bounds__(256) void ln_fused(
    const float* __restrict__ tmp, float* __restrict__ x,
    const float* __restrict__ g, const float* __restrict__ b,
    const float* __restrict__ phi, float* __restrict__ z) {
    const int row  = blockIdx.x * 4 + (threadIdx.x >> 6);
    const int lane = threadIdx.x & 63;
    const float* tr = tmp + (size_t)row * Ee;
    f32x4 v0 = *(const f32x4*)(tr + lane * 4);
    f32x4 v1 = *(const f32x4*)(tr + 256 + lane * 4);
    float s = v0.x + v0.y + v0.z + v0.w + v1.x + v1.y + v1.z + v1.w;
#pragma unroll
    for (int o = 32; o; o >>= 1) s += __shfl_xor(s, o);
    float mu = s * (1.f / 512.f);
    f32x4 d0 = {v0.x - mu, v0.y - mu, v0.z - mu, v0.w - mu};
    f32x4 d1 = {v1.x - mu, v1.y - mu, v1.z - mu, v1.w - mu};
    float q = d0.x * d0.x + d0.y * d0.y + d0.z * d0.z + d0.w * d0.w +
              d1.x * d1.x + d1.y * d1.y + d1.z * d1.z + d1.w * d1.w;
#pragma unroll
    for (int o = 32; o; o >>= 1) q += __shfl_xor(q, o);
    float rs = rsqrtf(q * (1.f / 512.f) + LN_EPS);
    f32x4 g0 = *(const f32x4*)(g + lane * 4);
    f32x4 b0 = *(const f32x4*)(b + lane * 4);
    f32x4 g1 = *(const f32x4*)(g + 256 + lane * 4);
    f32x4 b1v = *(const f32x4*)(b + 256 + lane * 4);
    f32x4 o0 = {d0.x * rs * g0.x + b0.x, d0.y * rs * g0.y + b0.y,
                d0.z * rs * g0.z + b0.z, d0.w * rs * g0.w + b0.w};
    f32x4 o1 = {d1.x * rs * g1.x + b1v.x, d1.y * rs * g1.y + b1v.y,
                d1.z * rs * g1.z + b1v.z, d1.w * rs * g1.w + b1v.w};
    *(f32x4*)(x + (size_t)row * Ee + lane * 4) = o0;
    *(f32x4*)(x + (size_t)row * Ee + 256 + lane * 4) = o1;
    if (z != nullptr && lane == 0) {
        z[(size_t)row * 4 + 0] = fastcos(o0.x) * fastcos(phi[0]);
        z[(size_t)row * 4 + 1] = fastcos(o0.y) * fastcos(phi[1]);
        z[(size_t)row * 4 + 2] = fastcos(o0.z) * fastcos(phi[2]);
        z[(size_t)row * 4 + 3] = fastcos(o0.w) * fastcos(phi[3]);
    }
}

// ---------------- parallel pool: partial sums over 64-row chunks --------
__global__ __launch_bounds__(256) void pool_part(const float* __restrict__ x,
                                                 float* __restrict__ part) {
    int bidx = blockIdx.x, ch = blockIdx.y;
    int t = threadIdx.x;
    float s0 = 0.f, s1 = 0.f;
    for (int s = 0; s < 64; ++s) {
        const float* row = x + ((size_t)bidx * Ss + ch * 64 + s) * Ee;
        s0 += row[t];
        s1 += row[t + 256];
    }
    float* pr = part + ((size_t)(bidx * 32 + ch)) * Ee;
    pr[t] = s0;
    pr[t + 256] = s1;
}

// ---------------- finish pool + classifier ----------------
__global__ __launch_bounds__(256) void cls_kernel(const float* __restrict__ part,
                                                  const float* __restrict__ clsW,
                                                  const float* __restrict__ clsb,
                                                  float* __restrict__ out) {
    int bidx = blockIdx.x;
    int t = threadIdx.x;
    float p0 = 0.f, p1 = 0.f;
    for (int ch = 0; ch < 32; ++ch) {
        const float* pr = part + ((size_t)(bidx * 32 + ch)) * Ee;
        p0 += pr[t];
        p1 += pr[t + 256];
    }
    p0 *= (1.f / float(Ss));
    p1 *= (1.f / float(Ss));
    __shared__ float red[256];
    for (int c = 0; c < Cc; ++c) {
        red[t] = p0 * clsW[(size_t)c * Ee + t] + p1 * clsW[(size_t)c * Ee + t + 256];
        __syncthreads();
        for (int s2 = 128; s2 > 0; s2 >>= 1) {
            if (t < s2) red[t] += red[t + s2];
            __syncthreads();
        }
        if (t == 0) out[bidx * Cc + c] = red[0] + clsb[c];
        __syncthreads();
    }
}

extern "C" void kernel_launch(void* const* d_in, const int* in_sizes, int n_in,
                              void* d_out, int out_size, void* d_ws, size_t ws_size,
                              hipStream_t stream) {
    const int*   tokens     = (const int*)d_in[0];
    const float* emb        = (const float*)d_in[1];
    const float* theta_attn = (const float*)d_in[2];
    const float* combine_W  = (const float*)d_in[3];
    const float* combine_b  = (const float*)d_in[4];
    const float* ln1_g      = (const float*)d_in[5];
    const float* ln1_b      = (const float*)d_in[6];
    const float* phi_ffn    = (const float*)d_in[7];
    const float* lin1_W     = (const float*)d_in[8];
    const float* lin1_b     = (const float*)d_in[9];
    const float* lin2_W     = (const float*)d_in[10];
    const float* lin2_b     = (const float*)d_in[11];
    const float* ln2_g      = (const float*)d_in[12];
    const float* ln2_b      = (const float*)d_in[13];
    const float* cls_W      = (const float*)d_in[14];
    const float* cls_b      = (const float*)d_in[15];
    float* out = (float*)d_out;

    float* pe   = (float*)d_ws;                 // 2048*512
    float* x    = pe + (size_t)Ss * Ee;         // 16384*512
    float* tmp  = x + (size_t)Nn * Ee;          // 16384*512
    float* z    = tmp + (size_t)Nn * Ee;        // 16384*4
    float* part = z + (size_t)Nn * 4;           // 8*32*512
    unsigned short* Wcb = (unsigned short*)(part + (size_t)Bb * 32 * Ee); // 6*512*512
    unsigned short* W2b = Wcb + (size_t)Ll * Ee * Ee;                     // 6*512*2048

    {
        int total = Ss * (Ee / 2);
        pe_kernel<<<(total + 255) / 256, 256, 0, stream>>>(pe);
    }
    {
        int total = Nn * Ee / 4;
        embed_kernel<<<(total + 255) / 256, 256, 0, stream>>>(tokens, emb, pe, x);
    }
    {
        int n4c = Ll * Ee * Ee / 4;
        cvt_bf16<<<(n4c + 255) / 256, 256, 0, stream>>>(combine_W, Wcb, n4c);
        int n42 = Ll * Ee * Ff / 4;
        cvt_bf16<<<(n42 + 255) / 256, 256, 0, stream>>>(lin2_W, W2b, n42);
    }

    dim3 ggrid(Nn / 128, Ee / 128);  // (128, 4)
    for (int l = 0; l < Ll; l++) {
        const float* thl  = theta_attn + (size_t)l * Ee;
        const unsigned short* cWl = Wcb + (size_t)l * Ee * Ee;
        const float* cbl  = combine_b + (size_t)l * Ee;
        const float* g1   = ln1_g + (size_t)l * Ee;
        const float* b1n  = ln1_b + (size_t)l * Ee;
        const float* phil = phi_ffn + (size_t)l * 4;
        const float* w1l  = lin1_W + (size_t)l * Ff * 4;
        const float* b1l  = lin1_b + (size_t)l * Ff;
        const unsigned short* w2l = W2b + (size_t)l * Ee * Ff;
        const float* b2l  = lin2_b + (size_t)l * Ee;
        const float* g2   = ln2_g + (size_t)l * Ee;
        const float* b2n  = ln2_b + (size_t)l * Ee;

        // tmp = x + cos(x+theta) @ Wc^T + cb
        gemm_mfma<1><<<ggrid, 256, 0, stream>>>(x, thl, nullptr, cWl, cbl, x,
                                                tmp, Nn, Ee);
        // x = LN(tmp); z = cos(x[:,:4])*cos(phi)
        ln_fused<<<Nn / 4, 256, 0, stream>>>(tmp, x, g1, b1n, phil, z);
        // tmp = x + relu(z@W1^T+b1) @ W2^T + b2
        gemm_mfma<2><<<ggrid, 256, 0, stream>>>(z, w1l, b1l, w2l, b2l, x,
                                                tmp, Nn, Ff);
        // x = LN(tmp)
        ln_fused<<<Nn / 4, 256, 0, stream>>>(tmp, x, g2, b2n, nullptr, nullptr);
    }

    pool_part<<<dim3(Bb, 32), 256, 0, stream>>>(x, part);
    cls_kernel<<<Bb, 256, 0, stream>>>(part, cls_W, cls_b, out);
}